// Round 5
// baseline (4460.001 us; speedup 1.0000x reference)
//
#include <hip/hip_runtime.h>

// Problem constants
#define B_ 32
#define S_ 64
#define T_ 65
#define D_ 256
#define HE 512    // encoder hidden
#define HD 1024   // decoder hidden
#define VV 32000

typedef __attribute__((ext_vector_type(8))) short bf16x8;
typedef __attribute__((ext_vector_type(4))) float f32x4;

__device__ inline unsigned short f2bf(float f) {
  unsigned int u = __float_as_uint(f);
  u += 0x7FFFu + ((u >> 16) & 1u);   // RNE
  return (unsigned short)(u >> 16);
}
__device__ inline float bf2f(short h) {
  return __uint_as_float(((unsigned int)(unsigned short)h) << 16);
}
__device__ inline float sigmf(float x) { return 1.0f / (1.0f + __expf(-x)); }

#define MFMA16(a,b,c) __builtin_amdgcn_mfma_f32_16x16x32_bf16((a),(b),(c),0,0,0)

// ---------------- mask dtype detection + dense int8 mask -------------------
// Element (0,0) of both masks is guaranteed 1 (lengths >= 1, prefix masks).
// Codes: 0=bool bytes, 1=int32, 2=int64, 3=f32, 4=bf16, 5=f16.
__device__ inline int mask_dtype(const unsigned char* m) {
  unsigned b0 = m[0], b1 = m[1], b2 = m[2], b3 = m[3], b4 = m[4];
  if (b0 == 1 && b1 == 1) return 0;
  if (b0 == 1) {
    if (b4 == 1) return 1;
    if (b4 == 0 && m[8] == 1) return 2;
    return 1;
  }
  if (b0 == 0x80 && b1 == 0x3F) return 4;
  if (b0 == 0x00 && b1 == 0x3C) return 5;
  if (b2 == 0x80 && b3 == 0x3F) return 3;
  return 1;
}
__device__ inline int mask_val(const unsigned char* m, int dt, int i) {
  switch (dt) {
    case 0: return m[i] != 0;
    case 1: return ((const int*)m)[i] != 0;
    case 2: return ((const long long*)m)[i] != 0;
    case 3: return ((const float*)m)[i] != 0.0f;
    default: return ((const unsigned short*)m)[i] != 0;
  }
}
__global__ void k_masks(const unsigned char* msrc, const unsigned char* mtgt,
                        signed char* o_src, signed char* o_tgt) {
  const unsigned char* m = blockIdx.x ? mtgt : msrc;
  signed char* o = blockIdx.x ? o_tgt : o_src;
  int n = blockIdx.x ? (B_ * T_) : (B_ * S_);
  int dt = mask_dtype(m);
  for (int i = threadIdx.x; i < n; i += blockDim.x)
    o[i] = (signed char)mask_val(m, dt, i);
}

// ---------------- fp32 -> bf16 weight conversion ---------------------------
struct CvtJobs {
  const float* src[12];
  short* dst[12];
  int n4[12];
};
__global__ __launch_bounds__(256) void k_convert(CvtJobs jb) {
  int j = blockIdx.y;
  const float4* s = (const float4*)jb.src[j];
  ushort4* d = (ushort4*)jb.dst[j];
  int n4 = jb.n4[j];
  for (int i = blockIdx.x * blockDim.x + threadIdx.x; i < n4;
       i += gridDim.x * blockDim.x) {
    float4 v = s[i];
    ushort4 o;
    o.x = f2bf(v.x); o.y = f2bf(v.y); o.z = f2bf(v.z); o.w = f2bf(v.w);
    d[i] = o;
  }
}

// ---------------- embedding gather -> bf16 ----------------------------------
__global__ __launch_bounds__(256) void k_gather(const int* sids, const int* tids,
                                                const float* es, const float* et,
                                                short* Xs, short* Xt) {
  int job = blockIdx.y;
  int rows = job ? (B_ * T_) : (B_ * S_);
  const int* ids = job ? tids : sids;
  const float* emb = job ? et : es;
  ushort4* X = (ushort4*)(job ? Xt : Xs);
  int total = rows * (D_ / 4);
  for (int i = blockIdx.x * blockDim.x + threadIdx.x; i < total;
       i += gridDim.x * blockDim.x) {
    int row = i >> 6;            // D_/4 == 64
    int c4 = i & 63;
    long id = ids[row];
    float4 v = ((const float4*)(emb + id * (long)D_))[c4];
    ushort4 o;
    o.x = f2bf(v.x); o.y = f2bf(v.y); o.z = f2bf(v.z); o.w = f2bf(v.w);
    X[(long)row * 64 + c4] = o;
  }
}

// ---------------- MFMA GEMM: C[M,N] = A[Mp,K](bf16) · B[N,K]^T + bias -------
// B from bf16 (Bw) or fp32 (Bwf, in-kernel cvt). C to bf16 (C) or fp32 (Cf).
template <bool B_F32, bool C_F32>
__global__ __launch_bounds__(256) void k_gemm(const short* __restrict__ A,
                                              const short* __restrict__ Bw,
                                              const float* __restrict__ Bwf,
                                              const float* __restrict__ bias,
                                              short* __restrict__ C,
                                              float* __restrict__ Cf,
                                              int M_out, int N, int K) {
  __shared__ short As[128 * 32];
  __shared__ short Bs[128 * 32];
  const int tid = threadIdx.x;
  const int wave = tid >> 6, lane = tid & 63;
  const int wm = wave >> 1, wn = wave & 1;
  const int r16 = lane & 15, kb = lane >> 4;
  const long m0 = (long)blockIdx.y * 128;
  const long n0 = (long)blockIdx.x * 128;

  const int ch0 = tid * 2, ch1 = ch0 + 1;
  const int ar0 = ch0 >> 2, ak0 = (ch0 & 3) * 8;
  const int ar1 = ch1 >> 2, ak1 = (ch1 & 3) * 8;

  f32x4 acc[4][4];
#pragma unroll
  for (int i = 0; i < 4; i++)
#pragma unroll
    for (int j = 0; j < 4; j++) acc[i][j] = (f32x4){0.f, 0.f, 0.f, 0.f};

  for (int kt = 0; kt < K; kt += 32) {
    bf16x8 va0 = *(const bf16x8*)(A + (m0 + ar0) * K + kt + ak0);
    bf16x8 va1 = *(const bf16x8*)(A + (m0 + ar1) * K + kt + ak1);
    bf16x8 vb0, vb1;
    if (B_F32) {
      const float* p0 = Bwf + (n0 + ar0) * K + kt + ak0;
      const float* p1 = Bwf + (n0 + ar1) * K + kt + ak1;
      float4 x0 = *(const float4*)p0, x1 = *(const float4*)(p0 + 4);
      float4 y0 = *(const float4*)p1, y1 = *(const float4*)(p1 + 4);
      vb0 = (bf16x8){(short)f2bf(x0.x), (short)f2bf(x0.y), (short)f2bf(x0.z),
                     (short)f2bf(x0.w), (short)f2bf(x1.x), (short)f2bf(x1.y),
                     (short)f2bf(x1.z), (short)f2bf(x1.w)};
      vb1 = (bf16x8){(short)f2bf(y0.x), (short)f2bf(y0.y), (short)f2bf(y0.z),
                     (short)f2bf(y0.w), (short)f2bf(y1.x), (short)f2bf(y1.y),
                     (short)f2bf(y1.z), (short)f2bf(y1.w)};
    } else {
      vb0 = *(const bf16x8*)(Bw + (n0 + ar0) * K + kt + ak0);
      vb1 = *(const bf16x8*)(Bw + (n0 + ar1) * K + kt + ak1);
    }
    __syncthreads();
    *(bf16x8*)(As + ar0 * 32 + ak0) = va0;
    *(bf16x8*)(As + ar1 * 32 + ak1) = va1;
    *(bf16x8*)(Bs + ar0 * 32 + ak0) = vb0;
    *(bf16x8*)(Bs + ar1 * 32 + ak1) = vb1;
    __syncthreads();
    bf16x8 av[4], bv[4];
#pragma unroll
    for (int i = 0; i < 4; i++)
      av[i] = *(const bf16x8*)(As + (wm * 64 + i * 16 + r16) * 32 + kb * 8);
#pragma unroll
    for (int j = 0; j < 4; j++)
      bv[j] = *(const bf16x8*)(Bs + (wn * 64 + j * 16 + r16) * 32 + kb * 8);
#pragma unroll
    for (int i = 0; i < 4; i++)
#pragma unroll
      for (int j = 0; j < 4; j++) acc[i][j] = MFMA16(av[i], bv[j], acc[i][j]);
  }
#pragma unroll
  for (int j = 0; j < 4; j++) {
    long gc = n0 + wn * 64 + j * 16 + r16;
    float bb = bias ? bias[gc] : 0.f;
#pragma unroll
    for (int i = 0; i < 4; i++) {
      long gr0 = m0 + wm * 64 + i * 16 + kb * 4;
#pragma unroll
      for (int r = 0; r < 4; r++) {
        long gr = gr0 + r;
        if (gr < M_out) {
          if (C_F32) Cf[gr * N + gc] = acc[i][j][r] + bb;
          else C[gr * N + gc] = (short)f2bf(acc[i][j][r] + bb);
        }
      }
    }
  }
}

// ---------------- fused LSTM step ------------------------------------------
// Grid (H/16, 1, ndir); 4 waves = 4 gate quadrants x one 16-col tile x B=32.
template <int NSRC, int K0S>
__global__ __launch_bounds__(256) void k_step(
    const short* __restrict__ Wf, const short* __restrict__ Wb_,
    const short* __restrict__ Arf, const short* __restrict__ Arb,
    const short* __restrict__ W2, const short* __restrict__ A2,
    const float* __restrict__ Pf, const float* __restrict__ Pb,
    const float* __restrict__ bias,
    float* __restrict__ Cstf, float* __restrict__ Cstb,
    short* __restrict__ Hwf, short* __restrict__ Hwb,
    short* __restrict__ Outb, int outLD, int outOffDir,
    const signed char* __restrict__ msk, int H, int step, int SeqLen) {
  const int dir = blockIdx.z;
  const short* W = dir ? Wb_ : Wf;
  const short* Ar = dir ? Arb : Arf;
  const float* P = dir ? Pb : Pf;
  float* Cst = dir ? Cstb : Cstf;
  short* Hw = dir ? Hwb : Hwf;
  const int t = dir ? (SeqLen - 1 - step) : step;

  const int q = threadIdx.x >> 6, lane = threadIdx.x & 63;
  const int r16 = lane & 15, kb = lane >> 4;
  const int n = q * H + blockIdx.x * 16 + r16;

  f32x4 acc0 = (f32x4){0.f, 0.f, 0.f, 0.f};
  f32x4 acc1 = (f32x4){0.f, 0.f, 0.f, 0.f};
  {
    const short* wr = W + (size_t)n * K0S;
#pragma unroll 8
    for (int k = kb * 8; k < K0S; k += 32) {
      bf16x8 bv = *(const bf16x8*)(wr + k);
      bf16x8 a0 = *(const bf16x8*)(Ar + r16 * K0S + k);
      bf16x8 a1 = *(const bf16x8*)(Ar + (16 + r16) * K0S + k);
      acc0 = MFMA16(a0, bv, acc0);
      acc1 = MFMA16(a1, bv, acc1);
    }
  }
  if (NSRC == 2) {
    const short* wr = W2 + (size_t)n * K0S;
#pragma unroll 8
    for (int k = kb * 8; k < K0S; k += 32) {
      bf16x8 bv = *(const bf16x8*)(wr + k);
      bf16x8 a0 = *(const bf16x8*)(A2 + r16 * K0S + k);
      bf16x8 a1 = *(const bf16x8*)(A2 + (16 + r16) * K0S + k);
      acc0 = MFMA16(a0, bv, acc0);
      acc1 = MFMA16(a1, bv, acc1);
    }
  }
  __shared__ float g_lds[4][2][16][16];
#pragma unroll
  for (int r = 0; r < 4; r++) {
    g_lds[q][0][kb * 4 + r][r16] = acc0[r];
    g_lds[q][1][kb * 4 + r][r16] = acc1[r];
  }
  __syncthreads();
  const int c = threadIdx.x & 15, br = threadIdx.x >> 4;
  const int j = blockIdx.x * 16 + c;
#pragma unroll
  for (int mt = 0; mt < 2; ++mt) {
    int b = mt * 16 + br;
    float g0 = g_lds[0][mt][br][c], g1 = g_lds[1][mt][br][c];
    float g2 = g_lds[2][mt][br][c], g3 = g_lds[3][mt][br][c];
    if (P) {
      const float* pr = P + (size_t)(b * SeqLen + t) * (4 * (size_t)H);
      g0 += pr[j]; g1 += pr[H + j]; g2 += pr[2 * H + j]; g3 += pr[3 * H + j];
    }
    if (bias) {
      g0 += bias[j]; g1 += bias[H + j]; g2 += bias[2 * H + j]; g3 += bias[3 * H + j];
    }
    float co = Cst[b * H + j];
    float c2 = sigmf(g1) * co + sigmf(g0) * tanhf(g2);
    float h2 = sigmf(g3) * tanhf(c2);
    bool valid = msk[b * SeqLen + t] != 0;
    const short* Aprev = (NSRC == 2) ? A2 : Ar;
    short hn = valid ? (short)f2bf(h2) : Aprev[b * H + j];
    if (valid) Cst[b * H + j] = c2;
    Hw[b * H + j] = hn;
    if (Outb)
      Outb[(size_t)(b * SeqLen + t) * outLD + outOffDir * dir + j] =
          valid ? hn : (short)0;
  }
}

// ---------------- decoder state init from encoder finals --------------------
__global__ __launch_bounds__(256) void k_decinit(const short* h0, const float* c0,
                                                 const short* h1, const float* c1f,
                                                 short* dh1, float* dc1,
                                                 short* dh2, float* dc2) {
  int i = blockIdx.x * 256 + threadIdx.x;
  if (i < B_ * HD) {
    int b = i >> 10, nn = i & 1023, d = nn >> 9, jj = nn & 511;
    int src = (d * B_ + b) * HE + jj;
    dh1[i] = h0[src];
    dc1[i] = c0[src];
    dh2[i] = h1[src];
    dc2[i] = c1f[src];
  }
}

// ---------------------------------------------------------------------------
extern "C" void kernel_launch(void* const* d_in, const int* in_sizes, int n_in,
                              void* d_out, int out_size, void* d_ws, size_t ws_size,
                              hipStream_t stream) {
  const int* src = (const int*)d_in[0];
  const unsigned char* msrc = (const unsigned char*)d_in[1];
  const int* tgt = (const int*)d_in[2];
  const unsigned char* mtgt = (const unsigned char*)d_in[3];
  const float* emb_s = (const float*)d_in[4];
  const float* emb_t = (const float*)d_in[5];
  const float* eW0f = (const float*)d_in[6];
  const float* eU0f = (const float*)d_in[7];
  const float* eb0f = (const float*)d_in[8];
  const float* eW0b = (const float*)d_in[9];
  const float* eU0b = (const float*)d_in[10];
  const float* eb0b = (const float*)d_in[11];
  const float* eW1f = (const float*)d_in[12];
  const float* eU1f = (const float*)d_in[13];
  const float* eb1f = (const float*)d_in[14];
  const float* eW1b = (const float*)d_in[15];
  const float* eU1b = (const float*)d_in[16];
  const float* eb1b = (const float*)d_in[17];
  const float* dW0 = (const float*)d_in[18];
  const float* dU0 = (const float*)d_in[19];
  const float* db0 = (const float*)d_in[20];
  const float* dW1 = (const float*)d_in[21];
  const float* dU1 = (const float*)d_in[22];
  const float* db1 = (const float*)d_in[23];
  const float* wW = (const float*)d_in[24];
  const float* wb = (const float*)d_in[25];
  (void)n_in; (void)in_sizes; (void)out_size; (void)ws_size;

  // ---- d_ws: ONLY douts (live during the final GEMM). 4.46 MB ----
  short* douts = (short*)d_ws;                       // [2176][1024] bf16

  // ---- d_out scratch (fp32 out buffer = 266 MB): all buffers here are ----
  // ---- dead before the final GEMM, which reads only douts + wW + wb.  ----
  char* po = (char*)d_out;
  size_t off = 0;
  auto alloc = [&](size_t bytes) -> char* {
    char* p = po + off;
    off += (bytes + 255) & ~(size_t)255;
    return p;
  };
  const size_t szW[12] = {
      (size_t)2048 * 256 * 2,  (size_t)2048 * 512 * 2,   // eW0f, eU0f
      (size_t)2048 * 256 * 2,  (size_t)2048 * 512 * 2,   // eW0b, eU0b
      (size_t)2048 * 1024 * 2, (size_t)2048 * 512 * 2,   // eW1f, eU1f
      (size_t)2048 * 1024 * 2, (size_t)2048 * 512 * 2,   // eW1b, eU1b
      (size_t)4096 * 256 * 2,  (size_t)4096 * 1024 * 2,  // dW0,  dU0
      (size_t)4096 * 1024 * 2, (size_t)4096 * 1024 * 2}; // dW1,  dU1
  short* Wb[12];
  for (int i = 0; i < 12; i++) Wb[i] = (short*)alloc(szW[i]);
  short* eW0f_b = Wb[0], *eU0f_b = Wb[1], *eW0b_b = Wb[2], *eU0b_b = Wb[3];
  short* eW1f_b = Wb[4], *eU1f_b = Wb[5], *eW1b_b = Wb[6], *eU1b_b = Wb[7];
  short* dW0_b = Wb[8], *dU0_b = Wb[9], *dW1_b = Wb[10], *dU1_b = Wb[11];
  short* Xs_b = (short*)alloc((size_t)2048 * 256 * 2);
  short* Xt_b = (short*)alloc((size_t)2176 * 256 * 2);
  short* X1_b = (short*)alloc((size_t)2048 * 1024 * 2);
  char* uni = alloc((size_t)2176 * 4096 * 4);        // P0 | P1 | Q0 (aliased)
  float* P0f = (float*)uni;
  float* P0b = P0f + (size_t)2048 * 2048;
  float* P1f = (float*)uni;
  float* P1b = P1f + (size_t)2048 * 2048;
  float* Q0 = (float*)uni;
  // zero-init block: encoder initial states
  char* zero_begin = po + off;
  short* encH0p0 = (short*)alloc((size_t)2 * B_ * HE * 2);
  float* encC0 = (float*)alloc((size_t)2 * B_ * HE * 4);
  short* encH1p0 = (short*)alloc((size_t)2 * B_ * HE * 2);
  float* encC1 = (float*)alloc((size_t)2 * B_ * HE * 4);
  size_t zero_bytes = (size_t)((po + off) - zero_begin);
  short* encH0p1 = (short*)alloc((size_t)2 * B_ * HE * 2);
  short* encH1p1 = (short*)alloc((size_t)2 * B_ * HE * 2);
  short* dH1p0 = (short*)alloc((size_t)B_ * HD * 2);
  short* dH1p1 = (short*)alloc((size_t)B_ * HD * 2);
  float* dC1 = (float*)alloc((size_t)B_ * HD * 4);
  short* dH2p0 = (short*)alloc((size_t)B_ * HD * 2);
  short* dH2p1 = (short*)alloc((size_t)B_ * HD * 2);
  float* dC2 = (float*)alloc((size_t)B_ * HD * 4);
  signed char* msk_s = (signed char*)alloc(B_ * S_);
  signed char* msk_t = (signed char*)alloc(B_ * T_);

  const short* SN = nullptr;
  const float* FN = nullptr;

  // 1) zero douts + encoder states; masks; weight cvt; gathers
  (void)hipMemsetAsync(douts, 0, (size_t)2176 * 1024 * 2, stream);
  (void)hipMemsetAsync(zero_begin, 0, zero_bytes, stream);
  k_masks<<<dim3(2), dim3(256), 0, stream>>>(msrc, mtgt, msk_s, msk_t);
  CvtJobs jb;
  const float* srcs[12] = {eW0f, eU0f, eW0b, eU0b, eW1f, eU1f,
                           eW1b, eU1b, dW0, dU0, dW1, dU1};
  int ns[12] = {2048 * 256, 2048 * 512, 2048 * 256, 2048 * 512,
                2048 * 1024, 2048 * 512, 2048 * 1024, 2048 * 512,
                4096 * 256, 4096 * 1024, 4096 * 1024, 4096 * 1024};
  for (int i = 0; i < 12; i++) { jb.src[i] = srcs[i]; jb.dst[i] = Wb[i]; jb.n4[i] = ns[i] / 4; }
  k_convert<<<dim3(1024, 12), 256, 0, stream>>>(jb);
  k_gather<<<dim3(544, 2), 256, 0, stream>>>(src, tgt, emb_s, emb_t, Xs_b, Xt_b);

  // 2) encoder layer-0 input projections (fp32 out)
  k_gemm<false, true><<<dim3(16, 16), 256, 0, stream>>>(
      Xs_b, eW0f_b, FN, eb0f, (short*)nullptr, P0f, 2048, 2048, 256);
  k_gemm<false, true><<<dim3(16, 16), 256, 0, stream>>>(
      Xs_b, eW0b_b, FN, eb0b, (short*)nullptr, P0b, 2048, 2048, 256);

  // 3) encoder layer 0 -> X1
  {
    int p = 0;
    for (int s = 0; s < S_; ++s) {
      const short* hr = p ? encH0p1 : encH0p0;
      short* hw = p ? encH0p0 : encH0p1;
      k_step<1, 512><<<dim3(32, 1, 2), 256, 0, stream>>>(
          eU0f_b, eU0b_b, hr, hr + B_ * HE, SN, SN, P0f, P0b, FN,
          encC0, encC0 + B_ * HE, hw, hw + B_ * HE,
          X1_b, 1024, 512, msk_s, HE, s, S_);
      p ^= 1;
    }
  }

  // 4) encoder layer-1 input projections (aliases P0 region; P0 dead)
  k_gemm<false, true><<<dim3(16, 16), 256, 0, stream>>>(
      X1_b, eW1f_b, FN, eb1f, (short*)nullptr, P1f, 2048, 2048, 1024);
  k_gemm<false, true><<<dim3(16, 16), 256, 0, stream>>>(
      X1_b, eW1b_b, FN, eb1b, (short*)nullptr, P1b, 2048, 2048, 1024);

  // 5) encoder layer 1 (finals only)
  {
    int p = 0;
    for (int s = 0; s < S_; ++s) {
      const short* hr = p ? encH1p1 : encH1p0;
      short* hw = p ? encH1p0 : encH1p1;
      k_step<1, 512><<<dim3(32, 1, 2), 256, 0, stream>>>(
          eU1f_b, eU1b_b, hr, hr + B_ * HE, SN, SN, P1f, P1b, FN,
          encC1, encC1 + B_ * HE, hw, hw + B_ * HE,
          (short*)nullptr, 0, 0, msk_s, HE, s, S_);
      p ^= 1;
    }
  }

  // 6) decoder init from encoder finals (parity-0 after 64 steps)
  k_decinit<<<dim3(128), 256, 0, stream>>>(encH0p0, encC0, encH1p0, encC1,
                                           dH1p0, dC1, dH2p0, dC2);

  // 7) decoder layer-0 input projection (aliases P1; P1 dead)
  k_gemm<false, true><<<dim3(32, 17), 256, 0, stream>>>(
      Xt_b, dW0_b, FN, db0, (short*)nullptr, Q0, 2176, 4096, 256);

  // 8) decoder: 65 steps of (layer0, layer1)
  {
    int p = 0;
    for (int t = 0; t < T_; ++t) {
      const short* h1r = p ? dH1p1 : dH1p0;
      short* h1w = p ? dH1p0 : dH1p1;
      const short* h2r = p ? dH2p1 : dH2p0;
      short* h2w = p ? dH2p0 : dH2p1;
      k_step<1, 1024><<<dim3(64, 1, 1), 256, 0, stream>>>(
          dU0_b, SN, h1r, SN, SN, SN, Q0, FN, FN,
          dC1, (float*)nullptr, h1w, (short*)nullptr,
          (short*)nullptr, 0, 0, msk_t, HD, t, T_);
      k_step<2, 1024><<<dim3(64, 1, 1), 256, 0, stream>>>(
          dW1_b, SN, h1w, SN, dU1_b, h2r, FN, FN, db1,
          dC2, (float*)nullptr, h2w, (short*)nullptr,
          douts, 1024, 0, msk_t, HD, t, T_);
      p ^= 1;
    }
  }

  // 9) logits = douts(bf16, d_ws) @ wW^T(fp32, in-kernel cvt) + wb
  //    -> FP32 d_out (reference output dtype is float32!).
  //    Reads only d_ws + inputs; all d_out scratch is dead by now.
  k_gemm<true, true><<<dim3(250, 17), 256, 0, stream>>>(
      douts, SN, wW, wb, (short*)nullptr, (float*)d_out, B_ * T_, VV, 1024);
}

// Round 6
// 4382.085 us; speedup vs baseline: 1.0178x; 1.0178x over previous
//
#include <hip/hip_runtime.h>

// Problem constants
#define B_ 32
#define S_ 64
#define T_ 65
#define D_ 256
#define HE 512    // encoder hidden
#define HD 1024   // decoder hidden
#define VV 32000

typedef __attribute__((ext_vector_type(8))) short bf16x8;
typedef __attribute__((ext_vector_type(4))) float f32x4;

__device__ inline unsigned short f2bf(float f) {
  unsigned int u = __float_as_uint(f);
  u += 0x7FFFu + ((u >> 16) & 1u);   // RNE
  return (unsigned short)(u >> 16);
}
__device__ inline float sigmf(float x) { return 1.0f / (1.0f + __expf(-x)); }

#define MFMA16(a,b,c) __builtin_amdgcn_mfma_f32_16x16x32_bf16((a),(b),(c),0,0,0)

// ---------------- software grid barrier (device-scope, replay-safe) --------
// One counter per barrier instance; counters zeroed via hipMemsetAsync each
// kernel_launch call. All blocks co-resident (grid <= 128 blocks on 256 CUs).
__device__ inline void gbar(int* ctr, int nblk) {
  __syncthreads();
  if (threadIdx.x == 0) {
    __hip_atomic_fetch_add(ctr, 1, __ATOMIC_ACQ_REL, __HIP_MEMORY_SCOPE_AGENT);
    while (__hip_atomic_load(ctr, __ATOMIC_ACQUIRE, __HIP_MEMORY_SCOPE_AGENT) <
           nblk) {
      __builtin_amdgcn_s_sleep(2);
    }
  }
  __syncthreads();
}

// ---------------- mask dtype detection + dense int8 mask -------------------
__device__ inline int mask_dtype(const unsigned char* m) {
  unsigned b0 = m[0], b1 = m[1], b2 = m[2], b3 = m[3], b4 = m[4];
  if (b0 == 1 && b1 == 1) return 0;
  if (b0 == 1) {
    if (b4 == 1) return 1;
    if (b4 == 0 && m[8] == 1) return 2;
    return 1;
  }
  if (b0 == 0x80 && b1 == 0x3F) return 4;
  if (b0 == 0x00 && b1 == 0x3C) return 5;
  if (b2 == 0x80 && b3 == 0x3F) return 3;
  return 1;
}
__device__ inline int mask_val(const unsigned char* m, int dt, int i) {
  switch (dt) {
    case 0: return m[i] != 0;
    case 1: return ((const int*)m)[i] != 0;
    case 2: return ((const long long*)m)[i] != 0;
    case 3: return ((const float*)m)[i] != 0.0f;
    default: return ((const unsigned short*)m)[i] != 0;
  }
}
__global__ void k_masks(const unsigned char* msrc, const unsigned char* mtgt,
                        signed char* o_src, signed char* o_tgt) {
  const unsigned char* m = blockIdx.x ? mtgt : msrc;
  signed char* o = blockIdx.x ? o_tgt : o_src;
  int n = blockIdx.x ? (B_ * T_) : (B_ * S_);
  int dt = mask_dtype(m);
  for (int i = threadIdx.x; i < n; i += blockDim.x)
    o[i] = (signed char)mask_val(m, dt, i);
}

// ---------------- fp32 -> bf16 weight conversion (13 tensors) --------------
struct CvtJobs {
  const float* src[13];
  short* dst[13];
  int n4[13];
};
__global__ __launch_bounds__(256) void k_convert(CvtJobs jb) {
  int j = blockIdx.y;
  const float4* s = (const float4*)jb.src[j];
  ushort4* d = (ushort4*)jb.dst[j];
  int n4 = jb.n4[j];
  for (int i = blockIdx.x * blockDim.x + threadIdx.x; i < n4;
       i += gridDim.x * blockDim.x) {
    float4 v = s[i];
    ushort4 o;
    o.x = f2bf(v.x); o.y = f2bf(v.y); o.z = f2bf(v.z); o.w = f2bf(v.w);
    d[i] = o;
  }
}

// ---------------- embedding gather -> bf16 ----------------------------------
__global__ __launch_bounds__(256) void k_gather(const int* sids, const int* tids,
                                                const float* es, const float* et,
                                                short* Xs, short* Xt) {
  int job = blockIdx.y;
  int rows = job ? (B_ * T_) : (B_ * S_);
  const int* ids = job ? tids : sids;
  const float* emb = job ? et : es;
  ushort4* X = (ushort4*)(job ? Xt : Xs);
  int total = rows * (D_ / 4);
  for (int i = blockIdx.x * blockDim.x + threadIdx.x; i < total;
       i += gridDim.x * blockDim.x) {
    int row = i >> 6;
    int c4 = i & 63;
    long id = ids[row];
    float4 v = ((const float4*)(emb + id * (long)D_))[c4];
    ushort4 o;
    o.x = f2bf(v.x); o.y = f2bf(v.y); o.z = f2bf(v.z); o.w = f2bf(v.w);
    X[(long)row * 64 + c4] = o;
  }
}

// ---------------- MFMA GEMM: C[M,N] = A[Mp,K](bf16) · B[N,K]^T + bias -------
template <bool B_F32, bool C_F32>
__global__ __launch_bounds__(256) void k_gemm(const short* __restrict__ A,
                                              const short* __restrict__ Bw,
                                              const float* __restrict__ Bwf,
                                              const float* __restrict__ bias,
                                              short* __restrict__ C,
                                              float* __restrict__ Cf,
                                              int M_out, int N, int K) {
  __shared__ short As[128 * 32];
  __shared__ short Bs[128 * 32];
  const int tid = threadIdx.x;
  const int wave = tid >> 6, lane = tid & 63;
  const int wm = wave >> 1, wn = wave & 1;
  const int r16 = lane & 15, kb = lane >> 4;
  const long m0 = (long)blockIdx.y * 128;
  const long n0 = (long)blockIdx.x * 128;

  const int ch0 = tid * 2, ch1 = ch0 + 1;
  const int ar0 = ch0 >> 2, ak0 = (ch0 & 3) * 8;
  const int ar1 = ch1 >> 2, ak1 = (ch1 & 3) * 8;

  f32x4 acc[4][4];
#pragma unroll
  for (int i = 0; i < 4; i++)
#pragma unroll
    for (int j = 0; j < 4; j++) acc[i][j] = (f32x4){0.f, 0.f, 0.f, 0.f};

  for (int kt = 0; kt < K; kt += 32) {
    bf16x8 va0 = *(const bf16x8*)(A + (m0 + ar0) * K + kt + ak0);
    bf16x8 va1 = *(const bf16x8*)(A + (m0 + ar1) * K + kt + ak1);
    bf16x8 vb0, vb1;
    if (B_F32) {
      const float* p0 = Bwf + (n0 + ar0) * K + kt + ak0;
      const float* p1 = Bwf + (n0 + ar1) * K + kt + ak1;
      float4 x0 = *(const float4*)p0, x1 = *(const float4*)(p0 + 4);
      float4 y0 = *(const float4*)p1, y1 = *(const float4*)(p1 + 4);
      vb0 = (bf16x8){(short)f2bf(x0.x), (short)f2bf(x0.y), (short)f2bf(x0.z),
                     (short)f2bf(x0.w), (short)f2bf(x1.x), (short)f2bf(x1.y),
                     (short)f2bf(x1.z), (short)f2bf(x1.w)};
      vb1 = (bf16x8){(short)f2bf(y0.x), (short)f2bf(y0.y), (short)f2bf(y0.z),
                     (short)f2bf(y0.w), (short)f2bf(y1.x), (short)f2bf(y1.y),
                     (short)f2bf(y1.z), (short)f2bf(y1.w)};
    } else {
      vb0 = *(const bf16x8*)(Bw + (n0 + ar0) * K + kt + ak0);
      vb1 = *(const bf16x8*)(Bw + (n0 + ar1) * K + kt + ak1);
    }
    __syncthreads();
    *(bf16x8*)(As + ar0 * 32 + ak0) = va0;
    *(bf16x8*)(As + ar1 * 32 + ak1) = va1;
    *(bf16x8*)(Bs + ar0 * 32 + ak0) = vb0;
    *(bf16x8*)(Bs + ar1 * 32 + ak1) = vb1;
    __syncthreads();
    bf16x8 av[4], bv[4];
#pragma unroll
    for (int i = 0; i < 4; i++)
      av[i] = *(const bf16x8*)(As + (wm * 64 + i * 16 + r16) * 32 + kb * 8);
#pragma unroll
    for (int j = 0; j < 4; j++)
      bv[j] = *(const bf16x8*)(Bs + (wn * 64 + j * 16 + r16) * 32 + kb * 8);
#pragma unroll
    for (int i = 0; i < 4; i++)
#pragma unroll
      for (int j = 0; j < 4; j++) acc[i][j] = MFMA16(av[i], bv[j], acc[i][j]);
  }
#pragma unroll
  for (int j = 0; j < 4; j++) {
    long gc = n0 + wn * 64 + j * 16 + r16;
    float bb = bias ? bias[gc] : 0.f;
#pragma unroll
    for (int i = 0; i < 4; i++) {
      long gr0 = m0 + wm * 64 + i * 16 + kb * 4;
#pragma unroll
      for (int r = 0; r < 4; r++) {
        long gr = gr0 + r;
        if (gr < M_out) {
          if (C_F32) Cf[gr * N + gc] = acc[i][j][r] + bb;
          else C[gr * N + gc] = (short)f2bf(acc[i][j][r] + bb);
        }
      }
    }
  }
}

// ---------------- persistent encoder layer (64 steps, both dirs) -----------
// Grid (HE/16=32, 2 dirs). H layout: [parity][dir][B][HE]. c in registers;
// final c written to Cfin[dir*B+b][HE]. P includes bias.
__global__ __launch_bounds__(256) void k_enc_persist(
    const short* __restrict__ Wf, const short* __restrict__ Wb_,
    short* __restrict__ H, const float* __restrict__ Pf,
    const float* __restrict__ Pb, short* __restrict__ Outb, int outLD,
    int outOffDir, float* __restrict__ Cfin,
    const signed char* __restrict__ msk, int* ctr) {
  const int dir = blockIdx.y;
  const short* W = dir ? Wb_ : Wf;
  const float* P = dir ? Pb : Pf;
  const int q = threadIdx.x >> 6, lane = threadIdx.x & 63;
  const int r16 = lane & 15, kb = lane >> 4;
  const int n = q * HE + blockIdx.x * 16 + r16;
  const short* wr = W + (size_t)n * HE;
  const int c = threadIdx.x & 15, br = threadIdx.x >> 4;
  const int j = blockIdx.x * 16 + c;
  const int nblk = gridDim.x * gridDim.y;
  __shared__ float g_lds[4][2][16][16];
  float creg[2] = {0.f, 0.f};

  for (int s = 0; s < S_; ++s) {
    const int t = dir ? (S_ - 1 - s) : s;
    const int rp = s & 1;
    const short* Ar = H + ((size_t)rp * 2 + dir) * (B_ * HE);
    short* Hw = H + ((size_t)(rp ^ 1) * 2 + dir) * (B_ * HE);

    f32x4 acc0 = (f32x4){0.f, 0.f, 0.f, 0.f};
    f32x4 acc1 = (f32x4){0.f, 0.f, 0.f, 0.f};
#pragma unroll 8
    for (int k = kb * 8; k < HE; k += 32) {
      bf16x8 bv = *(const bf16x8*)(wr + k);
      bf16x8 a0 = *(const bf16x8*)(Ar + r16 * HE + k);
      bf16x8 a1 = *(const bf16x8*)(Ar + (16 + r16) * HE + k);
      acc0 = MFMA16(a0, bv, acc0);
      acc1 = MFMA16(a1, bv, acc1);
    }
#pragma unroll
    for (int r = 0; r < 4; r++) {
      g_lds[q][0][kb * 4 + r][r16] = acc0[r];
      g_lds[q][1][kb * 4 + r][r16] = acc1[r];
    }
    __syncthreads();
#pragma unroll
    for (int mt = 0; mt < 2; ++mt) {
      int b = mt * 16 + br;
      const float* pr = P + (size_t)(b * S_ + t) * (4 * HE);
      float g0 = g_lds[0][mt][br][c] + pr[j];
      float g1 = g_lds[1][mt][br][c] + pr[HE + j];
      float g2 = g_lds[2][mt][br][c] + pr[2 * HE + j];
      float g3 = g_lds[3][mt][br][c] + pr[3 * HE + j];
      float co = creg[mt];
      float c2 = sigmf(g1) * co + sigmf(g0) * tanhf(g2);
      float h2 = sigmf(g3) * tanhf(c2);
      bool valid = msk[b * S_ + t] != 0;
      short hn = valid ? (short)f2bf(h2) : Ar[b * HE + j];
      if (valid) creg[mt] = c2;
      Hw[b * HE + j] = hn;
      if (Outb)
        Outb[(size_t)(b * S_ + t) * outLD + outOffDir * dir + j] =
            valid ? hn : (short)0;
    }
    if (s < S_ - 1) gbar(ctr + s, nblk);
  }
#pragma unroll
  for (int mt = 0; mt < 2; ++mt) {
    int b = mt * 16 + br;
    Cfin[(size_t)(dir * B_ + b) * HE + j] = creg[mt];
  }
}

// ---------------- persistent decoder (65 steps, pipelined 2 layers) --------
// Grid (HD/16=64, 2 roles). Phase k: role0 runs L0(t=k), role1 runs L1(t=k-1).
// H1/H2 layout: [parity][B][HD]. c in registers, init from dC1i/dC2i.
__global__ __launch_bounds__(256) void k_dec_persist(
    const short* __restrict__ dU0b, const short* __restrict__ dW1b,
    const short* __restrict__ dU1b, short* __restrict__ H1,
    short* __restrict__ H2, const float* __restrict__ Q0,
    const float* __restrict__ db1f, const float* __restrict__ dC1i,
    const float* __restrict__ dC2i, short* __restrict__ douts,
    const signed char* __restrict__ msk, int* ctr) {
  const int role = blockIdx.y;
  const int q = threadIdx.x >> 6, lane = threadIdx.x & 63;
  const int r16 = lane & 15, kb = lane >> 4;
  const int n = q * HD + blockIdx.x * 16 + r16;
  const int c = threadIdx.x & 15, br = threadIdx.x >> 4;
  const int j = blockIdx.x * 16 + c;
  __shared__ float g_lds[4][2][16][16];
  const float* Ci = role ? dC2i : dC1i;
  float creg[2];
  creg[0] = Ci[(size_t)br * HD + j];
  creg[1] = Ci[(size_t)(16 + br) * HD + j];
  const short* w0 = dU0b + (size_t)n * HD;
  const short* w1 = dW1b + (size_t)n * HD;
  const short* w2 = dU1b + (size_t)n * HD;

  for (int k = 0; k <= T_; ++k) {
    if (role == 0) {
      if (k <= T_ - 1) {
        const int t = k, rp = k & 1;
        const short* Ar = H1 + (size_t)rp * (B_ * HD);
        short* Hw = H1 + (size_t)(rp ^ 1) * (B_ * HD);
        f32x4 acc0 = (f32x4){0.f, 0.f, 0.f, 0.f};
        f32x4 acc1 = (f32x4){0.f, 0.f, 0.f, 0.f};
#pragma unroll 8
        for (int kk = kb * 8; kk < HD; kk += 32) {
          bf16x8 bv = *(const bf16x8*)(w0 + kk);
          bf16x8 a0 = *(const bf16x8*)(Ar + r16 * HD + kk);
          bf16x8 a1 = *(const bf16x8*)(Ar + (16 + r16) * HD + kk);
          acc0 = MFMA16(a0, bv, acc0);
          acc1 = MFMA16(a1, bv, acc1);
        }
#pragma unroll
        for (int r = 0; r < 4; r++) {
          g_lds[q][0][kb * 4 + r][r16] = acc0[r];
          g_lds[q][1][kb * 4 + r][r16] = acc1[r];
        }
        __syncthreads();
#pragma unroll
        for (int mt = 0; mt < 2; ++mt) {
          int b = mt * 16 + br;
          const float* pr = Q0 + (size_t)(b * T_ + t) * (4 * HD);
          float g0 = g_lds[0][mt][br][c] + pr[j];
          float g1 = g_lds[1][mt][br][c] + pr[HD + j];
          float g2 = g_lds[2][mt][br][c] + pr[2 * HD + j];
          float g3 = g_lds[3][mt][br][c] + pr[3 * HD + j];
          float co = creg[mt];
          float c2 = sigmf(g1) * co + sigmf(g0) * tanhf(g2);
          float h2 = sigmf(g3) * tanhf(c2);
          bool valid = msk[b * T_ + t] != 0;
          short hn = valid ? (short)f2bf(h2) : Ar[b * HD + j];
          if (valid) creg[mt] = c2;
          Hw[b * HD + j] = hn;
        }
      }
    } else {
      if (k >= 1) {
        const int t = k - 1, rp = t & 1;
        const short* X = H1 + (size_t)(k & 1) * (B_ * HD);   // h1 written L0(t)
        const short* Ar2 = H2 + (size_t)rp * (B_ * HD);
        short* Hw = H2 + (size_t)(rp ^ 1) * (B_ * HD);
        f32x4 acc0 = (f32x4){0.f, 0.f, 0.f, 0.f};
        f32x4 acc1 = (f32x4){0.f, 0.f, 0.f, 0.f};
#pragma unroll 8
        for (int kk = kb * 8; kk < HD; kk += 32) {
          bf16x8 bv = *(const bf16x8*)(w1 + kk);
          bf16x8 a0 = *(const bf16x8*)(X + r16 * HD + kk);
          bf16x8 a1 = *(const bf16x8*)(X + (16 + r16) * HD + kk);
          acc0 = MFMA16(a0, bv, acc0);
          acc1 = MFMA16(a1, bv, acc1);
        }
#pragma unroll 8
        for (int kk = kb * 8; kk < HD; kk += 32) {
          bf16x8 bv = *(const bf16x8*)(w2 + kk);
          bf16x8 a0 = *(const bf16x8*)(Ar2 + r16 * HD + kk);
          bf16x8 a1 = *(const bf16x8*)(Ar2 + (16 + r16) * HD + kk);
          acc0 = MFMA16(a0, bv, acc0);
          acc1 = MFMA16(a1, bv, acc1);
        }
#pragma unroll
        for (int r = 0; r < 4; r++) {
          g_lds[q][0][kb * 4 + r][r16] = acc0[r];
          g_lds[q][1][kb * 4 + r][r16] = acc1[r];
        }
        __syncthreads();
#pragma unroll
        for (int mt = 0; mt < 2; ++mt) {
          int b = mt * 16 + br;
          float g0 = g_lds[0][mt][br][c] + db1f[j];
          float g1 = g_lds[1][mt][br][c] + db1f[HD + j];
          float g2 = g_lds[2][mt][br][c] + db1f[2 * HD + j];
          float g3 = g_lds[3][mt][br][c] + db1f[3 * HD + j];
          float co = creg[mt];
          float c2 = sigmf(g1) * co + sigmf(g0) * tanhf(g2);
          float h2 = sigmf(g3) * tanhf(c2);
          bool valid = msk[b * T_ + t] != 0;
          short hn = valid ? (short)f2bf(h2) : Ar2[b * HD + j];
          if (valid) creg[mt] = c2;
          Hw[b * HD + j] = hn;
          douts[(size_t)(b * T_ + t) * HD + j] = valid ? hn : (short)0;
        }
      }
    }
    if (k < T_) gbar(ctr + k, gridDim.x * gridDim.y);
  }
}

// ---------------- decoder state init from encoder finals --------------------
__global__ __launch_bounds__(256) void k_decinit(const short* h0, const float* c0,
                                                 const short* h1, const float* c1f,
                                                 short* dh1, float* dc1,
                                                 short* dh2, float* dc2) {
  int i = blockIdx.x * 256 + threadIdx.x;
  if (i < B_ * HD) {
    int b = i >> 10, nn = i & 1023, d = nn >> 9, jj = nn & 511;
    int src = (d * B_ + b) * HE + jj;
    dh1[i] = h0[src];
    dc1[i] = c0[src];
    dh2[i] = h1[src];
    dc2[i] = c1f[src];
  }
}

// ---------------------------------------------------------------------------
extern "C" void kernel_launch(void* const* d_in, const int* in_sizes, int n_in,
                              void* d_out, int out_size, void* d_ws, size_t ws_size,
                              hipStream_t stream) {
  const int* src = (const int*)d_in[0];
  const unsigned char* msrc = (const unsigned char*)d_in[1];
  const int* tgt = (const int*)d_in[2];
  const unsigned char* mtgt = (const unsigned char*)d_in[3];
  const float* emb_s = (const float*)d_in[4];
  const float* emb_t = (const float*)d_in[5];
  const float* eW0f = (const float*)d_in[6];
  const float* eU0f = (const float*)d_in[7];
  const float* eb0f = (const float*)d_in[8];
  const float* eW0b = (const float*)d_in[9];
  const float* eU0b = (const float*)d_in[10];
  const float* eb0b = (const float*)d_in[11];
  const float* eW1f = (const float*)d_in[12];
  const float* eU1f = (const float*)d_in[13];
  const float* eb1f = (const float*)d_in[14];
  const float* eW1b = (const float*)d_in[15];
  const float* eU1b = (const float*)d_in[16];
  const float* eb1b = (const float*)d_in[17];
  const float* dW0 = (const float*)d_in[18];
  const float* dU0 = (const float*)d_in[19];
  const float* db0 = (const float*)d_in[20];
  const float* dW1 = (const float*)d_in[21];
  const float* dU1 = (const float*)d_in[22];
  const float* db1 = (const float*)d_in[23];
  const float* wW = (const float*)d_in[24];
  const float* wb = (const float*)d_in[25];
  (void)n_in; (void)in_sizes; (void)out_size; (void)ws_size;

  // ---- d_ws: douts + wW_b (both live during the final GEMM). ~70 MB ----
  short* douts = (short*)d_ws;                       // [2176][1024] bf16
  short* wW_b = (short*)((char*)d_ws + (size_t)2176 * 1024 * 2);  // [VV][1024]

  // ---- d_out scratch (266 MB): dead before the final GEMM ----
  char* po = (char*)d_out;
  size_t off = 0;
  auto alloc = [&](size_t bytes) -> char* {
    char* p = po + off;
    off += (bytes + 255) & ~(size_t)255;
    return p;
  };
  const size_t szW[12] = {
      (size_t)2048 * 256 * 2,  (size_t)2048 * 512 * 2,
      (size_t)2048 * 256 * 2,  (size_t)2048 * 512 * 2,
      (size_t)2048 * 1024 * 2, (size_t)2048 * 512 * 2,
      (size_t)2048 * 1024 * 2, (size_t)2048 * 512 * 2,
      (size_t)4096 * 256 * 2,  (size_t)4096 * 1024 * 2,
      (size_t)4096 * 1024 * 2, (size_t)4096 * 1024 * 2};
  short* Wb[12];
  for (int i = 0; i < 12; i++) Wb[i] = (short*)alloc(szW[i]);
  short* eW0f_b = Wb[0], *eU0f_b = Wb[1], *eW0b_b = Wb[2], *eU0b_b = Wb[3];
  short* eW1f_b = Wb[4], *eU1f_b = Wb[5], *eW1b_b = Wb[6], *eU1b_b = Wb[7];
  short* dW0_b = Wb[8], *dU0_b = Wb[9], *dW1_b = Wb[10], *dU1_b = Wb[11];
  short* Xs_b = (short*)alloc((size_t)2048 * 256 * 2);
  short* Xt_b = (short*)alloc((size_t)2176 * 256 * 2);
  short* X1_b = (short*)alloc((size_t)2048 * 1024 * 2);
  char* uni = alloc((size_t)2176 * 4096 * 4);        // P0 | P1 | Q0 (aliased)
  float* P0f = (float*)uni;
  float* P0b = P0f + (size_t)2048 * 2048;
  float* P1f = (float*)uni;
  float* P1b = P1f + (size_t)2048 * 2048;
  float* Q0 = (float*)uni;
  // zero block: barrier counters + encoder h states
  char* zero_begin = po + off;
  int* ctrs = (int*)alloc(256 * 4);
  short* encH0 = (short*)alloc((size_t)2 * 2 * B_ * HE * 2);  // [par][dir][B][HE]
  short* encH1 = (short*)alloc((size_t)2 * 2 * B_ * HE * 2);
  size_t zero_bytes = (size_t)((po + off) - zero_begin);
  float* Cfin0 = (float*)alloc((size_t)2 * B_ * HE * 4);
  float* Cfin1 = (float*)alloc((size_t)2 * B_ * HE * 4);
  short* dH1 = (short*)alloc((size_t)2 * B_ * HD * 2);        // [par][B][HD]
  short* dH2 = (short*)alloc((size_t)2 * B_ * HD * 2);
  float* dC1f = (float*)alloc((size_t)B_ * HD * 4);
  float* dC2f = (float*)alloc((size_t)B_ * HD * 4);
  signed char* msk_s = (signed char*)alloc(B_ * S_);
  signed char* msk_t = (signed char*)alloc(B_ * T_);

  const short* SN = nullptr;
  const float* FN = nullptr;

  // 1) zero: douts, counters+enc states; masks; weight cvt (incl wW); gathers
  (void)hipMemsetAsync(douts, 0, (size_t)2176 * 1024 * 2, stream);
  (void)hipMemsetAsync(zero_begin, 0, zero_bytes, stream);
  k_masks<<<dim3(2), dim3(256), 0, stream>>>(msrc, mtgt, msk_s, msk_t);
  CvtJobs jb;
  const float* srcs[13] = {eW0f, eU0f, eW0b, eU0b, eW1f, eU1f,
                           eW1b, eU1b, dW0, dU0, dW1, dU1, wW};
  short* dsts[13] = {Wb[0], Wb[1], Wb[2], Wb[3], Wb[4], Wb[5],
                     Wb[6], Wb[7], Wb[8], Wb[9], Wb[10], Wb[11], wW_b};
  int ns[13] = {2048 * 256, 2048 * 512, 2048 * 256, 2048 * 512,
                2048 * 1024, 2048 * 512, 2048 * 1024, 2048 * 512,
                4096 * 256, 4096 * 1024, 4096 * 1024, 4096 * 1024, VV * 1024};
  for (int i = 0; i < 13; i++) { jb.src[i] = srcs[i]; jb.dst[i] = dsts[i]; jb.n4[i] = ns[i] / 4; }
  k_convert<<<dim3(1024, 13), 256, 0, stream>>>(jb);
  k_gather<<<dim3(544, 2), 256, 0, stream>>>(src, tgt, emb_s, emb_t, Xs_b, Xt_b);

  // 2) encoder layer-0 input projections (fp32 out, bias folded)
  k_gemm<false, true><<<dim3(16, 16), 256, 0, stream>>>(
      Xs_b, eW0f_b, FN, eb0f, (short*)nullptr, P0f, 2048, 2048, 256);
  k_gemm<false, true><<<dim3(16, 16), 256, 0, stream>>>(
      Xs_b, eW0b_b, FN, eb0b, (short*)nullptr, P0b, 2048, 2048, 256);

  // 3) encoder layer 0 persistent (64 steps, 63 grid-bars) -> X1, Cfin0
  k_enc_persist<<<dim3(32, 2), 256, 0, stream>>>(
      eU0f_b, eU0b_b, encH0, P0f, P0b, X1_b, 1024, 512, Cfin0, msk_s, ctrs);

  // 4) encoder layer-1 input projections (alias P0; P0 dead)
  k_gemm<false, true><<<dim3(16, 16), 256, 0, stream>>>(
      X1_b, eW1f_b, FN, eb1f, (short*)nullptr, P1f, 2048, 2048, 1024);
  k_gemm<false, true><<<dim3(16, 16), 256, 0, stream>>>(
      X1_b, eW1b_b, FN, eb1b, (short*)nullptr, P1b, 2048, 2048, 1024);

  // 5) encoder layer 1 persistent (finals only) -> Cfin1
  k_enc_persist<<<dim3(32, 2), 256, 0, stream>>>(
      eU1f_b, eU1b_b, encH1, P1f, P1b, (short*)nullptr, 0, 0, Cfin1, msk_s,
      ctrs + 64);

  // 6) decoder init from encoder finals (parity-0 bases)
  k_decinit<<<dim3(128), 256, 0, stream>>>(encH0, Cfin0, encH1, Cfin1,
                                           dH1, dC1f, dH2, dC2f);

  // 7) decoder layer-0 input projection (alias P1; P1 dead; db0 folded)
  k_gemm<false, true><<<dim3(32, 17), 256, 0, stream>>>(
      Xt_b, dW0_b, FN, db0, (short*)nullptr, Q0, 2176, 4096, 256);

  // 8) decoder persistent: 65 steps x 2 layers, pipelined roles, 65 grid-bars
  k_dec_persist<<<dim3(64, 2), 256, 0, stream>>>(
      dU0_b, dW1_b, dU1_b, dH1, dH2, Q0, db1, dC1f, dC2f, douts, msk_t,
      ctrs + 128);

  // 9) logits = douts(bf16) @ wW_b^T(bf16) + wb -> fp32 d_out
  k_gemm<false, true><<<dim3(250, 17), 256, 0, stream>>>(
      douts, wW_b, FN, wb, (short*)nullptr, (float*)d_out, B_ * T_, VV, 1024);
}